// Round 4
// baseline (1527.678 us; speedup 1.0000x reference)
//
#include <hip/hip_runtime.h>
#include <hip/hip_bf16.h>

#define N_NODES 50000
#define N_EDGES 600000
#define DD      128
#define NGRAPHS 64
#define MPAD    50048   // 391*128; padded rows written but never consumed
#define SCB     512
#define NSCB    ((N_NODES + SCB - 1) / SCB)   // 98
#define LPAD    132     // f32 LDS row stride: +4 pad, keeps 16B alignment, spreads banks

typedef __attribute__((ext_vector_type(8))) short  short8;
typedef __attribute__((ext_vector_type(4))) float  float4v;

static __device__ __forceinline__ unsigned short f2bf_rne(float f) {
  unsigned u = __builtin_bit_cast(unsigned, f);
  u = (u + 0x7FFFu + ((u >> 16) & 1u)) >> 16;
  return (unsigned short)u;
}
static __device__ __forceinline__ float bf2f(unsigned short h) {
  unsigned u = ((unsigned)h) << 16;
  return __builtin_bit_cast(float, u);
}
static __device__ __forceinline__ float bflo(unsigned u) { return __builtin_bit_cast(float, u << 16); }
static __device__ __forceinline__ float bfhi(unsigned u) { return __builtin_bit_cast(float, u & 0xFFFF0000u); }

// ---------------- CSR build ----------------
__global__ __launch_bounds__(256) void count_kernel(const int* __restrict__ dst, int* __restrict__ cnt) {
  int i = blockIdx.x * 256 + threadIdx.x;
  if (i < N_EDGES) atomicAdd(&cnt[dst[i]], 1);
}

__global__ __launch_bounds__(SCB) void scanA_kernel(const int* __restrict__ cnt, int* __restrict__ loc,
                                                    int* __restrict__ bsum) {
  __shared__ int sm[SCB];
  int t = threadIdx.x;
  int i = blockIdx.x * SCB + t;
  int v = (i < N_NODES) ? cnt[i] : 0;
  sm[t] = v;
  __syncthreads();
  for (int ofs = 1; ofs < SCB; ofs <<= 1) {
    int u = (t >= ofs) ? sm[t - ofs] : 0;
    __syncthreads();
    sm[t] += u;
    __syncthreads();
  }
  if (i < N_NODES) loc[i] = sm[t] - v;
  if (t == SCB - 1) bsum[blockIdx.x] = sm[t];
}

__global__ __launch_bounds__(64) void scanB_kernel(const int* __restrict__ bsum, int* __restrict__ boff,
                                                   int* __restrict__ off_last) {
  if (threadIdx.x == 0) {
    int a = 0;
    for (int b = 0; b < NSCB; ++b) { boff[b] = a; a += bsum[b]; }
    *off_last = a;
  }
}

__global__ __launch_bounds__(SCB) void scanC_kernel(const int* __restrict__ loc, const int* __restrict__ boff,
                                                    const int* __restrict__ cnt, int* __restrict__ off,
                                                    int* __restrict__ nxt, float* __restrict__ dis) {
  int i = blockIdx.x * SCB + threadIdx.x;
  if (i < N_NODES) {
    int o = loc[i] + boff[blockIdx.x];
    off[i] = o; nxt[i] = o;
    dis[i] = rsqrtf((float)(cnt[i] + 1));   // deg includes self-loop
  }
}

__global__ __launch_bounds__(256) void fill_kernel(const int* __restrict__ src, const int* __restrict__ dst,
                                                   int* __restrict__ nxt, const float* __restrict__ dis,
                                                   int2* __restrict__ edge) {
  int i = blockIdx.x * 256 + threadIdx.x;
  if (i < N_EDGES) {
    int s = src[i], d = dst[i];
    int pos = atomicAdd(&nxt[d], 1);
    int2 p; p.x = s; p.y = __float_as_int(dis[s] * dis[d]);
    edge[pos] = p;
  }
}

__global__ __launch_bounds__(256) void bcount_kernel(const int* __restrict__ batch, int* __restrict__ gcnt) {
  int i = blockIdx.x * 256 + threadIdx.x;
  if (i < N_NODES) atomicAdd(&gcnt[batch[i]], 1);
}

// ---------------- W prep: split bf16 hi/lo, transposed to [conv][n][k] ----------------
__global__ __launch_bounds__(256) void wprep_kernel(const float* __restrict__ W1, const float* __restrict__ W2,
                                                    unsigned short* __restrict__ WH, unsigned short* __restrict__ WL) {
  int idx = blockIdx.x * 256 + threadIdx.x;
  if (idx >= 16 * DD * DD) return;
  int c = idx >> 14;          // conv index 0..15
  int r = idx & 16383;
  int n = r >> 7, k = r & 127;
  const float* W = (c & 1) ? W2 : W1;
  float v = W[((size_t)(c >> 1) << 14) + (size_t)k * DD + n];   // W[l][k][n]
  unsigned short h = f2bf_rne(v);
  WH[idx] = h;
  WL[idx] = f2bf_rne(v - bf2f(h));
}

// ---------------- GEMM0: T(bf16)[M x 128] = x(f32) @ W0, split-bf16 3-product ----------------
__global__ __launch_bounds__(128) void gemm_split_kernel(const float* __restrict__ A, unsigned short* __restrict__ T,
                                                         const unsigned short* __restrict__ WH,
                                                         const unsigned short* __restrict__ WL, int M) {
  const int lane = threadIdx.x & 63;
  const int wave = threadIdx.x >> 6;
  const int Rbase = blockIdx.x * 64 + wave * 32;
  const int lr = lane & 15;
  const int lg = lane >> 4;

  float4v acc[2][8];
#pragma unroll
  for (int i = 0; i < 2; ++i)
#pragma unroll
    for (int j = 0; j < 8; ++j) acc[i][j] = (float4v)0.f;

#pragma unroll
  for (int kk = 0; kk < 4; ++kk) {
    const int k0 = kk * 32 + lg * 8;
    short8 ah[2], al[2];
#pragma unroll
    for (int rf = 0; rf < 2; ++rf) {
      int row = Rbase + rf * 16 + lr;
      row = (row < M) ? row : (M - 1);
      const float* ap = A + (size_t)row * DD + k0;
      float4v x0 = *(const float4v*)ap;
      float4v x1 = *(const float4v*)(ap + 4);
      short8 h, l;
#pragma unroll
      for (int i = 0; i < 4; ++i) {
        unsigned short hb = f2bf_rne(x0[i]);
        h[i] = (short)hb; l[i] = (short)f2bf_rne(x0[i] - bf2f(hb));
      }
#pragma unroll
      for (int i = 0; i < 4; ++i) {
        unsigned short hb = f2bf_rne(x1[i]);
        h[4 + i] = (short)hb; l[4 + i] = (short)f2bf_rne(x1[i] - bf2f(hb));
      }
      ah[rf] = h; al[rf] = l;
    }
#pragma unroll
    for (int n = 0; n < 8; ++n) {
      const size_t wo = (size_t)(n * 16 + lr) * DD + k0;
      short8 bh = *(const short8*)(WH + wo);
      short8 bl = *(const short8*)(WL + wo);
#pragma unroll
      for (int rf = 0; rf < 2; ++rf) {
        acc[rf][n] = __builtin_amdgcn_mfma_f32_16x16x32_bf16(ah[rf], bh, acc[rf][n], 0, 0, 0);
        acc[rf][n] = __builtin_amdgcn_mfma_f32_16x16x32_bf16(al[rf], bh, acc[rf][n], 0, 0, 0);
        acc[rf][n] = __builtin_amdgcn_mfma_f32_16x16x32_bf16(ah[rf], bl, acc[rf][n], 0, 0, 0);
      }
    }
  }
#pragma unroll
  for (int rf = 0; rf < 2; ++rf) {
#pragma unroll
    for (int j = 0; j < 4; ++j) {
      int row = Rbase + rf * 16 + lg * 4 + j;
      unsigned short* tp = T + (size_t)row * DD;
#pragma unroll
      for (int n = 0; n < 8; ++n) tp[n * 16 + lr] = f2bf_rne(acc[rf][n][j]);
    }
  }
}

// ---------------- Fused: h = relu?(agg(T_c)+b) in LDS, then T_{c+1} = h @ W_{c+1} ----------------
__global__ __launch_bounds__(512) void fused_kernel(const unsigned* __restrict__ t, unsigned short* __restrict__ Tn,
                                                    const int2* __restrict__ edge,
                                                    const int* __restrict__ off, const float* __restrict__ dis,
                                                    const float* __restrict__ bias, int relu,
                                                    const unsigned short* __restrict__ WH,
                                                    const unsigned short* __restrict__ WL) {
  __shared__ float lh[64][LPAD];
  const int lane = threadIdx.x & 63;
  const int wave = threadIdx.x >> 6;
  const int rowbase = blockIdx.x * 64;

  // ---- agg phase: wave handles 8 rows
  float2 bb = *(const float2*)(bias + 2 * lane);
#pragma unroll 1
  for (int r = 0; r < 8; ++r) {
    int rl = wave * 8 + r;
    int n = rowbase + rl;
    float ax = 0.f, ay = 0.f;
    if (n < N_NODES) {
      float dn = dis[n];
      int e0 = off[n], e1 = off[n + 1];
      unsigned sv = t[(size_t)n * 64 + lane];
      float axA = dn * dn * bflo(sv), ayA = dn * dn * bfhi(sv);
      float axB = 0.f, ayB = 0.f;
      int e = e0;
      for (; e + 4 <= e1; e += 4) {
        int2 p0 = edge[e], p1 = edge[e + 1], p2 = edge[e + 2], p3 = edge[e + 3];
        unsigned v0 = t[(size_t)p0.x * 64 + lane];
        unsigned v1 = t[(size_t)p1.x * 64 + lane];
        unsigned v2 = t[(size_t)p2.x * 64 + lane];
        unsigned v3 = t[(size_t)p3.x * 64 + lane];
        float w0 = __int_as_float(p0.y), w1 = __int_as_float(p1.y);
        float w2 = __int_as_float(p2.y), w3 = __int_as_float(p3.y);
        axA += w0 * bflo(v0) + w2 * bflo(v2);
        ayA += w0 * bfhi(v0) + w2 * bfhi(v2);
        axB += w1 * bflo(v1) + w3 * bflo(v3);
        ayB += w1 * bfhi(v1) + w3 * bfhi(v3);
      }
      for (; e < e1; ++e) {
        int2 p0 = edge[e];
        unsigned v0 = t[(size_t)p0.x * 64 + lane];
        float w0 = __int_as_float(p0.y);
        axA += w0 * bflo(v0);
        ayA += w0 * bfhi(v0);
      }
      ax = axA + axB + bb.x; ay = ayA + ayB + bb.y;
      if (relu) { ax = fmaxf(ax, 0.f); ay = fmaxf(ay, 0.f); }
    }
    float2 o; o.x = ax; o.y = ay;
    *(float2*)&lh[rl][2 * lane] = o;
  }
  __syncthreads();

  // ---- gemm phase: wave = (row tile 0..3) x (col half 0..1)
  const int lr = lane & 15;
  const int lg = lane >> 4;
  const int tI = wave >> 1;
  const int nh = wave & 1;

  float4v acc[4];
#pragma unroll
  for (int n = 0; n < 4; ++n) acc[n] = (float4v)0.f;

#pragma unroll
  for (int kk = 0; kk < 4; ++kk) {
    const int k0 = kk * 32 + lg * 8;
    const float* ap = &lh[tI * 16 + lr][k0];
    float4v x0 = *(const float4v*)ap;
    float4v x1 = *(const float4v*)(ap + 4);
    short8 ah, al;
#pragma unroll
    for (int i = 0; i < 4; ++i) {
      unsigned short hb = f2bf_rne(x0[i]);
      ah[i] = (short)hb; al[i] = (short)f2bf_rne(x0[i] - bf2f(hb));
    }
#pragma unroll
    for (int i = 0; i < 4; ++i) {
      unsigned short hb = f2bf_rne(x1[i]);
      ah[4 + i] = (short)hb; al[4 + i] = (short)f2bf_rne(x1[i] - bf2f(hb));
    }
#pragma unroll
    for (int n = 0; n < 4; ++n) {
      const int col = nh * 64 + n * 16 + lr;
      const size_t wo = (size_t)col * DD + k0;
      short8 bh = *(const short8*)(WH + wo);
      short8 bl = *(const short8*)(WL + wo);
      acc[n] = __builtin_amdgcn_mfma_f32_16x16x32_bf16(ah, bh, acc[n], 0, 0, 0);
      acc[n] = __builtin_amdgcn_mfma_f32_16x16x32_bf16(al, bh, acc[n], 0, 0, 0);
      acc[n] = __builtin_amdgcn_mfma_f32_16x16x32_bf16(ah, bl, acc[n], 0, 0, 0);
    }
  }
#pragma unroll
  for (int j = 0; j < 4; ++j) {
    int row = rowbase + tI * 16 + lg * 4 + j;
    unsigned short* tp = Tn + (size_t)row * DD + nh * 64;
#pragma unroll
    for (int n = 0; n < 4; ++n) tp[n * 16 + lr] = f2bf_rne(acc[n][j]);
  }
}

// ---------------- Final conv agg fused with mean-pool partial sums ----------------
__global__ __launch_bounds__(256) void agg_pool_kernel(const unsigned* __restrict__ t,
                                                       const int2* __restrict__ edge,
                                                       const int* __restrict__ off, const float* __restrict__ dis,
                                                       const float* __restrict__ bias,
                                                       const int* __restrict__ batch,
                                                       float* __restrict__ gsum) {
  int wid = (int)((blockIdx.x * blockDim.x + threadIdx.x) >> 6);
  int lane = threadIdx.x & 63;
  if (wid >= N_NODES) return;
  int n = __builtin_amdgcn_readfirstlane(wid);
  float dn = dis[n];
  int e0 = off[n], e1 = off[n + 1];

  unsigned sv = t[(size_t)n * 64 + lane];
  float axA = dn * dn * bflo(sv), ayA = dn * dn * bfhi(sv);
  float axB = 0.f, ayB = 0.f;

  int e = e0;
  for (; e + 4 <= e1; e += 4) {
    int2 p0 = edge[e], p1 = edge[e + 1], p2 = edge[e + 2], p3 = edge[e + 3];
    unsigned v0 = t[(size_t)p0.x * 64 + lane];
    unsigned v1 = t[(size_t)p1.x * 64 + lane];
    unsigned v2 = t[(size_t)p2.x * 64 + lane];
    unsigned v3 = t[(size_t)p3.x * 64 + lane];
    float w0 = __int_as_float(p0.y), w1 = __int_as_float(p1.y);
    float w2 = __int_as_float(p2.y), w3 = __int_as_float(p3.y);
    axA += w0 * bflo(v0) + w2 * bflo(v2);
    ayA += w0 * bfhi(v0) + w2 * bfhi(v2);
    axB += w1 * bflo(v1) + w3 * bflo(v3);
    ayB += w1 * bfhi(v1) + w3 * bfhi(v3);
  }
  for (; e < e1; ++e) {
    int2 p0 = edge[e];
    unsigned v0 = t[(size_t)p0.x * 64 + lane];
    float w0 = __int_as_float(p0.y);
    axA += w0 * bflo(v0);
    ayA += w0 * bfhi(v0);
  }
  float2 bb = *(const float2*)(bias + 2 * lane);
  float ax = axA + axB + bb.x, ay = ayA + ayB + bb.y;
  int g = batch[n];
  atomicAdd(&gsum[(size_t)g * DD + 2 * lane], ax);
  atomicAdd(&gsum[(size_t)g * DD + 2 * lane + 1], ay);
}

__global__ __launch_bounds__(128) void pool2_kernel(const float* __restrict__ gsum, const int* __restrict__ gcnt,
                                                    float* __restrict__ out) {
  int g = blockIdx.x, d = threadIdx.x;
  int c = gcnt[g];
  out[(size_t)g * DD + d] = gsum[(size_t)g * DD + d] / (float)(c > 0 ? c : 1);
}

extern "C" void kernel_launch(void* const* d_in, const int* in_sizes, int n_in,
                              void* d_out, int out_size, void* d_ws, size_t ws_size,
                              hipStream_t stream) {
  const float* x   = (const float*)d_in[0];
  const int*   ei  = (const int*)d_in[1];
  const int*   bat = (const int*)d_in[2];
  const float* W1  = (const float*)d_in[3];
  const float* b1  = (const float*)d_in[4];
  const float* W2  = (const float*)d_in[5];
  const float* b2  = (const float*)d_in[6];
  const int* srcv = ei;
  const int* dstv = ei + N_EDGES;

  char* p = (char*)d_ws;
  auto alloc = [&](size_t bytes) -> char* {
    char* r = p;
    p += (bytes + 255) & ~(size_t)255;
    return r;
  };
  int*            cnt  = (int*)alloc((size_t)N_NODES * 4);
  int*            off  = (int*)alloc((size_t)(N_NODES + 1) * 4);
  int*            nxt  = (int*)alloc((size_t)N_NODES * 4);
  float*          dis  = (float*)alloc((size_t)N_NODES * 4);
  int*            loc  = (int*)alloc((size_t)N_NODES * 4);
  int*            bsum = (int*)alloc((size_t)NSCB * 4);
  int*            boff = (int*)alloc((size_t)NSCB * 4);
  int2*           edge = (int2*)alloc((size_t)N_EDGES * 8);
  unsigned short* WH   = (unsigned short*)alloc((size_t)16 * DD * DD * 2);
  unsigned short* WL   = (unsigned short*)alloc((size_t)16 * DD * DD * 2);
  unsigned short* T0   = (unsigned short*)alloc((size_t)MPAD * DD * 2);
  unsigned short* T1   = (unsigned short*)alloc((size_t)MPAD * DD * 2);
  float*          gsum = (float*)alloc((size_t)NGRAPHS * DD * 4);
  int*            gcnt = (int*)alloc((size_t)NGRAPHS * 4);
  (void)ws_size; (void)in_sizes; (void)n_in; (void)out_size;

  hipMemsetAsync(cnt, 0, (size_t)N_NODES * 4, stream);
  hipMemsetAsync(gsum, 0, (size_t)NGRAPHS * DD * 4 + 256, stream);  // gsum + gcnt (adjacent)
  count_kernel<<<(N_EDGES + 255) / 256, 256, 0, stream>>>(dstv, cnt);
  scanA_kernel<<<NSCB, SCB, 0, stream>>>(cnt, loc, bsum);
  scanB_kernel<<<1, 64, 0, stream>>>(bsum, boff, &off[N_NODES]);
  scanC_kernel<<<NSCB, SCB, 0, stream>>>(loc, boff, cnt, off, nxt, dis);
  fill_kernel<<<(N_EDGES + 255) / 256, 256, 0, stream>>>(srcv, dstv, nxt, dis, edge);
  bcount_kernel<<<(N_NODES + 255) / 256, 256, 0, stream>>>(bat, gcnt);
  wprep_kernel<<<(16 * DD * DD + 255) / 256, 256, 0, stream>>>(W1, W2, WH, WL);

  unsigned short* Ts[2] = {T0, T1};
  gemm_split_kernel<<<MPAD / 64, 128, 0, stream>>>(x, T0, WH, WL, N_NODES);
  for (int c = 0; c < 15; ++c) {
    const float* bias = (c & 1) ? (b2 + (size_t)(c >> 1) * DD) : (b1 + (size_t)(c >> 1) * DD);
    fused_kernel<<<MPAD / 64, 512, 0, stream>>>((const unsigned*)Ts[c & 1], Ts[(c + 1) & 1], edge, off, dis,
                                                bias, (c & 1) ? 0 : 1,
                                                WH + (size_t)(c + 1) * DD * DD, WL + (size_t)(c + 1) * DD * DD);
  }
  // conv 15 output (T1 holds its pre-agg transform): agg + bias, fused with pool partials
  agg_pool_kernel<<<(N_NODES * 64) / 256, 256, 0, stream>>>((const unsigned*)Ts[15 & 1], edge, off, dis,
                                                            b2 + 7 * DD, bat, gsum);
  pool2_kernel<<<NGRAPHS, 128, 0, stream>>>(gsum, gcnt, (float*)d_out);
}

// Round 6
// 1084.863 us; speedup vs baseline: 1.4082x; 1.4082x over previous
//
#include <hip/hip_runtime.h>
#include <hip/hip_bf16.h>

#define N_NODES 50000
#define N_EDGES 600000
#define DD      128
#define NGRAPHS 64
#define MPAD    50048   // 391*128; padded rows written but never consumed
#define SCB     512
#define NSCB    ((N_NODES + SCB - 1) / SCB)   // 98

typedef __attribute__((ext_vector_type(8))) short  short8;
typedef __attribute__((ext_vector_type(4))) float  float4v;

static __device__ __forceinline__ unsigned short f2bf_rne(float f) {
  unsigned u = __builtin_bit_cast(unsigned, f);
  u = (u + 0x7FFFu + ((u >> 16) & 1u)) >> 16;
  return (unsigned short)u;
}
static __device__ __forceinline__ float bf2f(unsigned short h) {
  unsigned u = ((unsigned)h) << 16;
  return __builtin_bit_cast(float, u);
}
static __device__ __forceinline__ float bflo(unsigned u) { return __builtin_bit_cast(float, u << 16); }
static __device__ __forceinline__ float bfhi(unsigned u) { return __builtin_bit_cast(float, u & 0xFFFF0000u); }

// ---------------- CSR build ----------------
__global__ __launch_bounds__(256) void count_kernel(const int* __restrict__ dst, int* __restrict__ cnt) {
  int i = blockIdx.x * 256 + threadIdx.x;
  if (i < N_EDGES) atomicAdd(&cnt[dst[i]], 1);
}

__global__ __launch_bounds__(SCB) void scanA_kernel(const int* __restrict__ cnt, int* __restrict__ loc,
                                                    int* __restrict__ bsum) {
  __shared__ int sm[SCB];
  int t = threadIdx.x;
  int i = blockIdx.x * SCB + t;
  int v = (i < N_NODES) ? cnt[i] : 0;
  sm[t] = v;
  __syncthreads();
  for (int ofs = 1; ofs < SCB; ofs <<= 1) {
    int u = (t >= ofs) ? sm[t - ofs] : 0;
    __syncthreads();
    sm[t] += u;
    __syncthreads();
  }
  if (i < N_NODES) loc[i] = sm[t] - v;
  if (t == SCB - 1) bsum[blockIdx.x] = sm[t];
}

__global__ __launch_bounds__(64) void scanB_kernel(const int* __restrict__ bsum, int* __restrict__ boff,
                                                   int* __restrict__ off_last) {
  if (threadIdx.x == 0) {
    int a = 0;
    for (int b = 0; b < NSCB; ++b) { boff[b] = a; a += bsum[b]; }
    *off_last = a;
  }
}

__global__ __launch_bounds__(SCB) void scanC_kernel(const int* __restrict__ loc, const int* __restrict__ boff,
                                                    const int* __restrict__ cnt, int* __restrict__ off,
                                                    int* __restrict__ nxt, float* __restrict__ dis) {
  int i = blockIdx.x * SCB + threadIdx.x;
  if (i < N_NODES) {
    int o = loc[i] + boff[blockIdx.x];
    off[i] = o; nxt[i] = o;
    dis[i] = rsqrtf((float)(cnt[i] + 1));   // deg includes self-loop
  }
}

__global__ __launch_bounds__(256) void fill_kernel(const int* __restrict__ src, const int* __restrict__ dst,
                                                   int* __restrict__ nxt, const float* __restrict__ dis,
                                                   int2* __restrict__ edge) {
  int i = blockIdx.x * 256 + threadIdx.x;
  if (i < N_EDGES) {
    int s = src[i], d = dst[i];
    int pos = atomicAdd(&nxt[d], 1);
    int2 p; p.x = s; p.y = __float_as_int(dis[s] * dis[d]);
    edge[pos] = p;
  }
}

// batch is sorted: per-graph counts via binary search (NO atomics — sorted batch
// makes per-node atomicAdd a same-address serialization disaster, measured 234us)
__global__ __launch_bounds__(64) void gseg_kernel(const int* __restrict__ batch, int* __restrict__ gcnt) {
  int g = threadIdx.x;
  int lo = 0, hi = N_NODES;
  while (lo < hi) { int m = (lo + hi) >> 1; if (batch[m] < g) lo = m + 1; else hi = m; }
  int s = lo;
  lo = 0; hi = N_NODES;
  int g1 = g + 1;
  while (lo < hi) { int m = (lo + hi) >> 1; if (batch[m] < g1) lo = m + 1; else hi = m; }
  gcnt[g] = lo - s;
}

// ---------------- W prep: split bf16 hi/lo, transposed to [conv][n][k] ----------------
__global__ __launch_bounds__(256) void wprep_kernel(const float* __restrict__ W1, const float* __restrict__ W2,
                                                    unsigned short* __restrict__ WH, unsigned short* __restrict__ WL) {
  int idx = blockIdx.x * 256 + threadIdx.x;
  if (idx >= 16 * DD * DD) return;
  int c = idx >> 14;          // conv index 0..15
  int r = idx & 16383;
  int n = r >> 7, k = r & 127;
  const float* W = (c & 1) ? W2 : W1;
  float v = W[((size_t)(c >> 1) << 14) + (size_t)k * DD + n];   // W[l][k][n]
  unsigned short h = f2bf_rne(v);
  WH[idx] = h;
  WL[idx] = f2bf_rne(v - bf2f(h));
}

// ---------------- GEMM0: T(bf16)[M x 128] = x(f32) @ W0, split-bf16 3-product ----------------
__global__ __launch_bounds__(128) void gemm_split_kernel(const float* __restrict__ A, unsigned short* __restrict__ T,
                                                         const unsigned short* __restrict__ WH,
                                                         const unsigned short* __restrict__ WL, int M) {
  const int lane = threadIdx.x & 63;
  const int wave = threadIdx.x >> 6;
  const int Rbase = blockIdx.x * 64 + wave * 32;
  const int lr = lane & 15;
  const int lg = lane >> 4;

  float4v acc[2][8];
#pragma unroll
  for (int i = 0; i < 2; ++i)
#pragma unroll
    for (int j = 0; j < 8; ++j) acc[i][j] = (float4v)0.f;

#pragma unroll
  for (int kk = 0; kk < 4; ++kk) {
    const int k0 = kk * 32 + lg * 8;
    short8 ah[2], al[2];
#pragma unroll
    for (int rf = 0; rf < 2; ++rf) {
      int row = Rbase + rf * 16 + lr;
      row = (row < M) ? row : (M - 1);
      const float* ap = A + (size_t)row * DD + k0;
      float4v x0 = *(const float4v*)ap;
      float4v x1 = *(const float4v*)(ap + 4);
      short8 h, l;
#pragma unroll
      for (int i = 0; i < 4; ++i) {
        unsigned short hb = f2bf_rne(x0[i]);
        h[i] = (short)hb; l[i] = (short)f2bf_rne(x0[i] - bf2f(hb));
      }
#pragma unroll
      for (int i = 0; i < 4; ++i) {
        unsigned short hb = f2bf_rne(x1[i]);
        h[4 + i] = (short)hb; l[4 + i] = (short)f2bf_rne(x1[i] - bf2f(hb));
      }
      ah[rf] = h; al[rf] = l;
    }
#pragma unroll
    for (int n = 0; n < 8; ++n) {
      const size_t wo = (size_t)(n * 16 + lr) * DD + k0;
      short8 bh = *(const short8*)(WH + wo);
      short8 bl = *(const short8*)(WL + wo);
#pragma unroll
      for (int rf = 0; rf < 2; ++rf) {
        acc[rf][n] = __builtin_amdgcn_mfma_f32_16x16x32_bf16(ah[rf], bh, acc[rf][n], 0, 0, 0);
        acc[rf][n] = __builtin_amdgcn_mfma_f32_16x16x32_bf16(al[rf], bh, acc[rf][n], 0, 0, 0);
        acc[rf][n] = __builtin_amdgcn_mfma_f32_16x16x32_bf16(ah[rf], bl, acc[rf][n], 0, 0, 0);
      }
    }
  }
#pragma unroll
  for (int rf = 0; rf < 2; ++rf) {
#pragma unroll
    for (int j = 0; j < 4; ++j) {
      int row = Rbase + rf * 16 + lg * 4 + j;
      unsigned short* tp = T + (size_t)row * DD;
#pragma unroll
      for (int n = 0; n < 8; ++n) tp[n * 16 + lr] = f2bf_rne(acc[rf][n][j]);
    }
  }
}

// ---------------- GEMM (inner convs): T(bf16) = H(bf16) @ W, split-B 2-product (A exact) ----------------
__global__ __launch_bounds__(128) void gemm_bf16_kernel(const unsigned short* __restrict__ H, unsigned short* __restrict__ T,
                                                        const unsigned short* __restrict__ WH,
                                                        const unsigned short* __restrict__ WL, int M) {
  const int lane = threadIdx.x & 63;
  const int wave = threadIdx.x >> 6;
  const int Rbase = blockIdx.x * 64 + wave * 32;
  const int lr = lane & 15;
  const int lg = lane >> 4;

  float4v acc[2][8];
#pragma unroll
  for (int i = 0; i < 2; ++i)
#pragma unroll
    for (int j = 0; j < 8; ++j) acc[i][j] = (float4v)0.f;

#pragma unroll
  for (int kk = 0; kk < 4; ++kk) {
    const int k0 = kk * 32 + lg * 8;
    short8 ah[2];
#pragma unroll
    for (int rf = 0; rf < 2; ++rf) {
      int row = Rbase + rf * 16 + lr;
      row = (row < M) ? row : (M - 1);
      ah[rf] = *(const short8*)(H + (size_t)row * DD + k0);
    }
#pragma unroll
    for (int n = 0; n < 8; ++n) {
      const size_t wo = (size_t)(n * 16 + lr) * DD + k0;
      short8 bh = *(const short8*)(WH + wo);
      short8 bl = *(const short8*)(WL + wo);
#pragma unroll
      for (int rf = 0; rf < 2; ++rf) {
        acc[rf][n] = __builtin_amdgcn_mfma_f32_16x16x32_bf16(ah[rf], bh, acc[rf][n], 0, 0, 0);
        acc[rf][n] = __builtin_amdgcn_mfma_f32_16x16x32_bf16(ah[rf], bl, acc[rf][n], 0, 0, 0);
      }
    }
  }
#pragma unroll
  for (int rf = 0; rf < 2; ++rf) {
#pragma unroll
    for (int j = 0; j < 4; ++j) {
      int row = Rbase + rf * 16 + lg * 4 + j;
      unsigned short* tp = T + (size_t)row * DD;
#pragma unroll
      for (int n = 0; n < 8; ++n) tp[n * 16 + lr] = f2bf_rne(acc[rf][n][j]);
    }
  }
}

// ---------------- Aggregation: H(bf16 packed) = relu?( b + dis^2*t[n] + sum_e w_e t[src_e] ) ----------------
__global__ __launch_bounds__(256) void agg_kernel(const unsigned* __restrict__ t, unsigned* __restrict__ H,
                                                  const int2* __restrict__ edge,
                                                  const int* __restrict__ off, const float* __restrict__ dis,
                                                  const float* __restrict__ bias, int relu) {
  int wid = (int)((blockIdx.x * blockDim.x + threadIdx.x) >> 6);
  int lane = threadIdx.x & 63;
  if (wid >= N_NODES) return;
  int n = __builtin_amdgcn_readfirstlane(wid);
  float dn = dis[n];
  int e0 = off[n], e1 = off[n + 1];

  unsigned sv = t[(size_t)n * 64 + lane];
  float axA = dn * dn * bflo(sv), ayA = dn * dn * bfhi(sv);
  float axB = 0.f, ayB = 0.f;

  int e = e0;
  for (; e + 8 <= e1; e += 8) {
    int2 p0 = edge[e], p1 = edge[e + 1], p2 = edge[e + 2], p3 = edge[e + 3];
    int2 p4 = edge[e + 4], p5 = edge[e + 5], p6 = edge[e + 6], p7 = edge[e + 7];
    unsigned v0 = t[(size_t)p0.x * 64 + lane];
    unsigned v1 = t[(size_t)p1.x * 64 + lane];
    unsigned v2 = t[(size_t)p2.x * 64 + lane];
    unsigned v3 = t[(size_t)p3.x * 64 + lane];
    unsigned v4 = t[(size_t)p4.x * 64 + lane];
    unsigned v5 = t[(size_t)p5.x * 64 + lane];
    unsigned v6 = t[(size_t)p6.x * 64 + lane];
    unsigned v7 = t[(size_t)p7.x * 64 + lane];
    float w0 = __int_as_float(p0.y), w1 = __int_as_float(p1.y);
    float w2 = __int_as_float(p2.y), w3 = __int_as_float(p3.y);
    float w4 = __int_as_float(p4.y), w5 = __int_as_float(p5.y);
    float w6 = __int_as_float(p6.y), w7 = __int_as_float(p7.y);
    axA += w0 * bflo(v0) + w2 * bflo(v2) + w4 * bflo(v4) + w6 * bflo(v6);
    ayA += w0 * bfhi(v0) + w2 * bfhi(v2) + w4 * bfhi(v4) + w6 * bfhi(v6);
    axB += w1 * bflo(v1) + w3 * bflo(v3) + w5 * bflo(v5) + w7 * bflo(v7);
    ayB += w1 * bfhi(v1) + w3 * bfhi(v3) + w5 * bfhi(v5) + w7 * bfhi(v7);
  }
  for (; e + 4 <= e1; e += 4) {
    int2 p0 = edge[e], p1 = edge[e + 1], p2 = edge[e + 2], p3 = edge[e + 3];
    unsigned v0 = t[(size_t)p0.x * 64 + lane];
    unsigned v1 = t[(size_t)p1.x * 64 + lane];
    unsigned v2 = t[(size_t)p2.x * 64 + lane];
    unsigned v3 = t[(size_t)p3.x * 64 + lane];
    float w0 = __int_as_float(p0.y), w1 = __int_as_float(p1.y);
    float w2 = __int_as_float(p2.y), w3 = __int_as_float(p3.y);
    axA += w0 * bflo(v0) + w2 * bflo(v2);
    ayA += w0 * bfhi(v0) + w2 * bfhi(v2);
    axB += w1 * bflo(v1) + w3 * bflo(v3);
    ayB += w1 * bfhi(v1) + w3 * bfhi(v3);
  }
  for (; e < e1; ++e) {
    int2 p0 = edge[e];
    unsigned v0 = t[(size_t)p0.x * 64 + lane];
    float w0 = __int_as_float(p0.y);
    axA += w0 * bflo(v0);
    ayA += w0 * bfhi(v0);
  }
  float2 bb = *(const float2*)(bias + 2 * lane);
  float ax = axA + axB + bb.x, ay = ayA + ayB + bb.y;
  if (relu) { ax = fmaxf(ax, 0.f); ay = fmaxf(ay, 0.f); }
  unsigned o = (unsigned)f2bf_rne(ax) | ((unsigned)f2bf_rne(ay) << 16);
  H[(size_t)n * 64 + lane] = o;
}

// ---------------- Final conv agg fused with mean-pool partial sums (f32, no h rounding) ----------------
__global__ __launch_bounds__(256) void agg_pool_kernel(const unsigned* __restrict__ t,
                                                       const int2* __restrict__ edge,
                                                       const int* __restrict__ off, const float* __restrict__ dis,
                                                       const float* __restrict__ bias,
                                                       const int* __restrict__ batch,
                                                       float* __restrict__ gsum) {
  int wid = (int)((blockIdx.x * blockDim.x + threadIdx.x) >> 6);
  int lane = threadIdx.x & 63;
  if (wid >= N_NODES) return;
  int n = __builtin_amdgcn_readfirstlane(wid);
  float dn = dis[n];
  int e0 = off[n], e1 = off[n + 1];

  unsigned sv = t[(size_t)n * 64 + lane];
  float axA = dn * dn * bflo(sv), ayA = dn * dn * bfhi(sv);
  float axB = 0.f, ayB = 0.f;

  int e = e0;
  for (; e + 4 <= e1; e += 4) {
    int2 p0 = edge[e], p1 = edge[e + 1], p2 = edge[e + 2], p3 = edge[e + 3];
    unsigned v0 = t[(size_t)p0.x * 64 + lane];
    unsigned v1 = t[(size_t)p1.x * 64 + lane];
    unsigned v2 = t[(size_t)p2.x * 64 + lane];
    unsigned v3 = t[(size_t)p3.x * 64 + lane];
    float w0 = __int_as_float(p0.y), w1 = __int_as_float(p1.y);
    float w2 = __int_as_float(p2.y), w3 = __int_as_float(p3.y);
    axA += w0 * bflo(v0) + w2 * bflo(v2);
    ayA += w0 * bfhi(v0) + w2 * bfhi(v2);
    axB += w1 * bflo(v1) + w3 * bflo(v3);
    ayB += w1 * bfhi(v1) + w3 * bfhi(v3);
  }
  for (; e < e1; ++e) {
    int2 p0 = edge[e];
    unsigned v0 = t[(size_t)p0.x * 64 + lane];
    float w0 = __int_as_float(p0.y);
    axA += w0 * bflo(v0);
    ayA += w0 * bfhi(v0);
  }
  float2 bb = *(const float2*)(bias + 2 * lane);
  float ax = axA + axB + bb.x, ay = ayA + ayB + bb.y;
  int g = batch[n];
  atomicAdd(&gsum[(size_t)g * DD + 2 * lane], ax);
  atomicAdd(&gsum[(size_t)g * DD + 2 * lane + 1], ay);
}

__global__ __launch_bounds__(128) void pool2_kernel(const float* __restrict__ gsum, const int* __restrict__ gcnt,
                                                    float* __restrict__ out) {
  int g = blockIdx.x, d = threadIdx.x;
  int c = gcnt[g];
  out[(size_t)g * DD + d] = gsum[(size_t)g * DD + d] / (float)(c > 0 ? c : 1);
}

extern "C" void kernel_launch(void* const* d_in, const int* in_sizes, int n_in,
                              void* d_out, int out_size, void* d_ws, size_t ws_size,
                              hipStream_t stream) {
  const float* x   = (const float*)d_in[0];
  const int*   ei  = (const int*)d_in[1];
  const int*   bat = (const int*)d_in[2];
  const float* W1  = (const float*)d_in[3];
  const float* b1  = (const float*)d_in[4];
  const float* W2  = (const float*)d_in[5];
  const float* b2  = (const float*)d_in[6];
  const int* srcv = ei;
  const int* dstv = ei + N_EDGES;

  char* p = (char*)d_ws;
  auto alloc = [&](size_t bytes) -> char* {
    char* r = p;
    p += (bytes + 255) & ~(size_t)255;
    return r;
  };
  int*            cnt  = (int*)alloc((size_t)N_NODES * 4);
  int*            off  = (int*)alloc((size_t)(N_NODES + 1) * 4);
  int*            nxt  = (int*)alloc((size_t)N_NODES * 4);
  float*          dis  = (float*)alloc((size_t)N_NODES * 4);
  int*            loc  = (int*)alloc((size_t)N_NODES * 4);
  int*            bsum = (int*)alloc((size_t)NSCB * 4);
  int*            boff = (int*)alloc((size_t)NSCB * 4);
  int2*           edge = (int2*)alloc((size_t)N_EDGES * 8);
  unsigned short* WH   = (unsigned short*)alloc((size_t)16 * DD * DD * 2);
  unsigned short* WL   = (unsigned short*)alloc((size_t)16 * DD * DD * 2);
  unsigned short* T    = (unsigned short*)alloc((size_t)MPAD * DD * 2);
  unsigned*       H    = (unsigned*)alloc((size_t)MPAD * 64 * 4);
  float*          gsum = (float*)alloc((size_t)NGRAPHS * DD * 4);
  int*            gcnt = (int*)alloc((size_t)NGRAPHS * 4);
  (void)ws_size; (void)in_sizes; (void)n_in; (void)out_size;

  hipMemsetAsync(cnt, 0, (size_t)N_NODES * 4, stream);
  hipMemsetAsync(gsum, 0, (size_t)NGRAPHS * DD * 4, stream);
  count_kernel<<<(N_EDGES + 255) / 256, 256, 0, stream>>>(dstv, cnt);
  scanA_kernel<<<NSCB, SCB, 0, stream>>>(cnt, loc, bsum);
  scanB_kernel<<<1, 64, 0, stream>>>(bsum, boff, &off[N_NODES]);
  scanC_kernel<<<NSCB, SCB, 0, stream>>>(loc, boff, cnt, off, nxt, dis);
  fill_kernel<<<(N_EDGES + 255) / 256, 256, 0, stream>>>(srcv, dstv, nxt, dis, edge);
  gseg_kernel<<<1, 64, 0, stream>>>(bat, gcnt);
  wprep_kernel<<<(16 * DD * DD + 255) / 256, 256, 0, stream>>>(W1, W2, WH, WL);

  gemm_split_kernel<<<MPAD / 64, 128, 0, stream>>>(x, T, WH, WL, N_NODES);
  for (int c = 0; c < 15; ++c) {
    const float* bias = (c & 1) ? (b2 + (size_t)(c >> 1) * DD) : (b1 + (size_t)(c >> 1) * DD);
    agg_kernel<<<(N_NODES * 64) / 256, 256, 0, stream>>>((const unsigned*)T, H, edge, off, dis,
                                                         bias, (c & 1) ? 0 : 1);
    gemm_bf16_kernel<<<MPAD / 64, 128, 0, stream>>>((const unsigned short*)H, T,
                                                    WH + (size_t)(c + 1) * DD * DD,
                                                    WL + (size_t)(c + 1) * DD * DD, N_NODES);
  }
  // conv 15: agg + bias fused with pool partials (f32 path, no rounding)
  agg_pool_kernel<<<(N_NODES * 64) / 256, 256, 0, stream>>>((const unsigned*)T, edge, off, dis,
                                                            b2 + 7 * DD, bat, gsum);
  pool2_kernel<<<NGRAPHS, 128, 0, stream>>>(gsum, gcnt, (float*)d_out);
}

// Round 8
// 1002.518 us; speedup vs baseline: 1.5238x; 1.0821x over previous
//
#include <hip/hip_runtime.h>
#include <hip/hip_bf16.h>

#define N_NODES 50000
#define N_EDGES 600000
#define DD      128
#define NGRAPHS 64
#define MPAD    50048   // 391*128; padded rows written but never consumed
#define SCB     512
#define NSCB    ((N_NODES + SCB - 1) / SCB)   // 98

typedef __attribute__((ext_vector_type(8))) short  short8;
typedef __attribute__((ext_vector_type(4))) float  float4v;

static __device__ __forceinline__ unsigned short f2bf_rne(float f) {
  unsigned u = __builtin_bit_cast(unsigned, f);
  u = (u + 0x7FFFu + ((u >> 16) & 1u)) >> 16;
  return (unsigned short)u;
}
static __device__ __forceinline__ float bf2f(unsigned short h) {
  unsigned u = ((unsigned)h) << 16;
  return __builtin_bit_cast(float, u);
}
static __device__ __forceinline__ float bflo(unsigned u) { return __builtin_bit_cast(float, u << 16); }
static __device__ __forceinline__ float bfhi(unsigned u) { return __builtin_bit_cast(float, u & 0xFFFF0000u); }

// ---------------- CSR build ----------------
__global__ __launch_bounds__(256) void count_kernel(const int* __restrict__ dst, int* __restrict__ cnt) {
  int i = blockIdx.x * 256 + threadIdx.x;
  if (i < N_EDGES) atomicAdd(&cnt[dst[i]], 1);
}

__global__ __launch_bounds__(SCB) void scanA_kernel(const int* __restrict__ cnt, int* __restrict__ loc,
                                                    int* __restrict__ bsum) {
  __shared__ int sm[SCB];
  int t = threadIdx.x;
  int i = blockIdx.x * SCB + t;
  int v = (i < N_NODES) ? cnt[i] : 0;
  sm[t] = v;
  __syncthreads();
  for (int ofs = 1; ofs < SCB; ofs <<= 1) {
    int u = (t >= ofs) ? sm[t - ofs] : 0;
    __syncthreads();
    sm[t] += u;
    __syncthreads();
  }
  if (i < N_NODES) loc[i] = sm[t] - v;
  if (t == SCB - 1) bsum[blockIdx.x] = sm[t];
}

__global__ __launch_bounds__(64) void scanB_kernel(const int* __restrict__ bsum, int* __restrict__ boff,
                                                   int* __restrict__ off_last) {
  if (threadIdx.x == 0) {
    int a = 0;
    for (int b = 0; b < NSCB; ++b) { boff[b] = a; a += bsum[b]; }
    *off_last = a;
  }
}

__global__ __launch_bounds__(SCB) void scanC_kernel(const int* __restrict__ loc, const int* __restrict__ boff,
                                                    const int* __restrict__ cnt, int* __restrict__ off,
                                                    int* __restrict__ nxt, float* __restrict__ dis) {
  int i = blockIdx.x * SCB + threadIdx.x;
  if (i < N_NODES) {
    int o = loc[i] + boff[blockIdx.x];
    off[i] = o; nxt[i] = o;
    dis[i] = rsqrtf((float)(cnt[i] + 1));   // deg includes self-loop
  }
}

__global__ __launch_bounds__(256) void fill_kernel(const int* __restrict__ src, const int* __restrict__ dst,
                                                   int* __restrict__ nxt, const float* __restrict__ dis,
                                                   int2* __restrict__ edge) {
  int i = blockIdx.x * 256 + threadIdx.x;
  if (i < N_EDGES) {
    int s = src[i], d = dst[i];
    int pos = atomicAdd(&nxt[d], 1);
    int2 p; p.x = s; p.y = __float_as_int(dis[s] * dis[d]);
    edge[pos] = p;
  }
}

// batch sorted: per-graph counts via binary search (no atomics — sorted batch makes
// per-node atomicAdd a same-address serialization disaster, measured 234us in R4)
__global__ __launch_bounds__(64) void gseg_kernel(const int* __restrict__ batch, int* __restrict__ gcnt) {
  int g = threadIdx.x;
  int lo = 0, hi = N_NODES;
  while (lo < hi) { int m = (lo + hi) >> 1; if (batch[m] < g) lo = m + 1; else hi = m; }
  int s = lo;
  lo = 0; hi = N_NODES;
  int g1 = g + 1;
  while (lo < hi) { int m = (lo + hi) >> 1; if (batch[m] < g1) lo = m + 1; else hi = m; }
  gcnt[g] = lo - s;
}

// ---------------- W prep: split bf16 hi/lo, transposed to [conv][n][k] ----------------
__global__ __launch_bounds__(256) void wprep_kernel(const float* __restrict__ W1, const float* __restrict__ W2,
                                                    unsigned short* __restrict__ WH, unsigned short* __restrict__ WL) {
  int idx = blockIdx.x * 256 + threadIdx.x;
  if (idx >= 16 * DD * DD) return;
  int c = idx >> 14;          // conv index 0..15
  int r = idx & 16383;
  int n = r >> 7, k = r & 127;
  const float* W = (c & 1) ? W2 : W1;
  float v = W[((size_t)(c >> 1) << 14) + (size_t)k * DD + n];   // W[l][k][n]
  unsigned short h = f2bf_rne(v);
  WH[idx] = h;
  WL[idx] = f2bf_rne(v - bf2f(h));
}

// ---------------- GEMM0: T(bf16)[M x 128] = x(f32) @ W0, split-bf16 3-product ----------------
__global__ __launch_bounds__(128) void gemm_split_kernel(const float* __restrict__ A, unsigned short* __restrict__ T,
                                                         const unsigned short* __restrict__ WH,
                                                         const unsigned short* __restrict__ WL, int M) {
  const int lane = threadIdx.x & 63;
  const int wave = threadIdx.x >> 6;
  const int Rbase = blockIdx.x * 64 + wave * 32;
  const int lr = lane & 15;
  const int lg = lane >> 4;

  float4v acc[2][8];
#pragma unroll
  for (int i = 0; i < 2; ++i)
#pragma unroll
    for (int j = 0; j < 8; ++j) acc[i][j] = (float4v)0.f;

#pragma unroll
  for (int kk = 0; kk < 4; ++kk) {
    const int k0 = kk * 32 + lg * 8;
    short8 ah[2], al[2];
#pragma unroll
    for (int rf = 0; rf < 2; ++rf) {
      int row = Rbase + rf * 16 + lr;
      row = (row < M) ? row : (M - 1);
      const float* ap = A + (size_t)row * DD + k0;
      float4v x0 = *(const float4v*)ap;
      float4v x1 = *(const float4v*)(ap + 4);
      short8 h, l;
#pragma unroll
      for (int i = 0; i < 4; ++i) {
        unsigned short hb = f2bf_rne(x0[i]);
        h[i] = (short)hb; l[i] = (short)f2bf_rne(x0[i] - bf2f(hb));
      }
#pragma unroll
      for (int i = 0; i < 4; ++i) {
        unsigned short hb = f2bf_rne(x1[i]);
        h[4 + i] = (short)hb; l[4 + i] = (short)f2bf_rne(x1[i] - bf2f(hb));
      }
      ah[rf] = h; al[rf] = l;
    }
#pragma unroll
    for (int n = 0; n < 8; ++n) {
      const size_t wo = (size_t)(n * 16 + lr) * DD + k0;
      short8 bh = *(const short8*)(WH + wo);
      short8 bl = *(const short8*)(WL + wo);
#pragma unroll
      for (int rf = 0; rf < 2; ++rf) {
        acc[rf][n] = __builtin_amdgcn_mfma_f32_16x16x32_bf16(ah[rf], bh, acc[rf][n], 0, 0, 0);
        acc[rf][n] = __builtin_amdgcn_mfma_f32_16x16x32_bf16(al[rf], bh, acc[rf][n], 0, 0, 0);
        acc[rf][n] = __builtin_amdgcn_mfma_f32_16x16x32_bf16(ah[rf], bl, acc[rf][n], 0, 0, 0);
      }
    }
  }
#pragma unroll
  for (int rf = 0; rf < 2; ++rf) {
#pragma unroll
    for (int j = 0; j < 4; ++j) {
      int row = Rbase + rf * 16 + lg * 4 + j;
      unsigned short* tp = T + (size_t)row * DD;
#pragma unroll
      for (int n = 0; n < 8; ++n) tp[n * 16 + lr] = f2bf_rne(acc[rf][n][j]);
    }
  }
}

// ---------------- GEMM (inner convs): T(bf16) = H(bf16) @ W, split-B 2-product (A exact) ----------------
__global__ __launch_bounds__(128) void gemm_bf16_kernel(const unsigned short* __restrict__ H, unsigned short* __restrict__ T,
                                                        const unsigned short* __restrict__ WH,
                                                        const unsigned short* __restrict__ WL, int M) {
  const int lane = threadIdx.x & 63;
  const int wave = threadIdx.x >> 6;
  const int Rbase = blockIdx.x * 64 + wave * 32;
  const int lr = lane & 15;
  const int lg = lane >> 4;

  float4v acc[2][8];
#pragma unroll
  for (int i = 0; i < 2; ++i)
#pragma unroll
    for (int j = 0; j < 8; ++j) acc[i][j] = (float4v)0.f;

#pragma unroll
  for (int kk = 0; kk < 4; ++kk) {
    const int k0 = kk * 32 + lg * 8;
    short8 ah[2];
#pragma unroll
    for (int rf = 0; rf < 2; ++rf) {
      int row = Rbase + rf * 16 + lr;
      row = (row < M) ? row : (M - 1);
      ah[rf] = *(const short8*)(H + (size_t)row * DD + k0);
    }
#pragma unroll
    for (int n = 0; n < 8; ++n) {
      const size_t wo = (size_t)(n * 16 + lr) * DD + k0;
      short8 bh = *(const short8*)(WH + wo);
      short8 bl = *(const short8*)(WL + wo);
#pragma unroll
      for (int rf = 0; rf < 2; ++rf) {
        acc[rf][n] = __builtin_amdgcn_mfma_f32_16x16x32_bf16(ah[rf], bh, acc[rf][n], 0, 0, 0);
        acc[rf][n] = __builtin_amdgcn_mfma_f32_16x16x32_bf16(ah[rf], bl, acc[rf][n], 0, 0, 0);
      }
    }
  }
#pragma unroll
  for (int rf = 0; rf < 2; ++rf) {
#pragma unroll
    for (int j = 0; j < 4; ++j) {
      int row = Rbase + rf * 16 + lg * 4 + j;
      unsigned short* tp = T + (size_t)row * DD;
#pragma unroll
      for (int n = 0; n < 8; ++n) tp[n * 16 + lr] = f2bf_rne(acc[rf][n][j]);
    }
  }
}

// ---------------- Aggregation: H(bf16 packed) = relu?( b + dis^2*t[n] + sum_e w_e t[src_e] ) ----------------
__global__ __launch_bounds__(256) void agg_kernel(const unsigned* __restrict__ t, unsigned* __restrict__ H,
                                                  const int2* __restrict__ edge,
                                                  const int* __restrict__ off, const float* __restrict__ dis,
                                                  const float* __restrict__ bias, int relu) {
  int wid = (int)((blockIdx.x * blockDim.x + threadIdx.x) >> 6);
  int lane = threadIdx.x & 63;
  if (wid >= N_NODES) return;
  int n = __builtin_amdgcn_readfirstlane(wid);
  float dn = dis[n];
  int e0 = off[n], e1 = off[n + 1];

  unsigned sv = t[(size_t)n * 64 + lane];
  float axA = dn * dn * bflo(sv), ayA = dn * dn * bfhi(sv);
  float axB = 0.f, ayB = 0.f;

  int e = e0;
  for (; e + 4 <= e1; e += 4) {
    int2 p0 = edge[e], p1 = edge[e + 1], p2 = edge[e + 2], p3 = edge[e + 3];
    unsigned v0 = t[(size_t)p0.x * 64 + lane];
    unsigned v1 = t[(size_t)p1.x * 64 + lane];
    unsigned v2 = t[(size_t)p2.x * 64 + lane];
    unsigned v3 = t[(size_t)p3.x * 64 + lane];
    float w0 = __int_as_float(p0.y), w1 = __int_as_float(p1.y);
    float w2 = __int_as_float(p2.y), w3 = __int_as_float(p3.y);
    axA += w0 * bflo(v0) + w2 * bflo(v2);
    ayA += w0 * bfhi(v0) + w2 * bfhi(v2);
    axB += w1 * bflo(v1) + w3 * bflo(v3);
    ayB += w1 * bfhi(v1) + w3 * bfhi(v3);
  }
  for (; e < e1; ++e) {
    int2 p0 = edge[e];
    unsigned v0 = t[(size_t)p0.x * 64 + lane];
    float w0 = __int_as_float(p0.y);
    axA += w0 * bflo(v0);
    ayA += w0 * bfhi(v0);
  }
  float2 bb = *(const float2*)(bias + 2 * lane);
  float ax = axA + axB + bb.x, ay = ayA + ayB + bb.y;
  if (relu) { ax = fmaxf(ax, 0.f); ay = fmaxf(ay, 0.f); }
  unsigned o = (unsigned)f2bf_rne(ax) | ((unsigned)f2bf_rne(ay) << 16);
  H[(size_t)n * 64 + lane] = o;
}

// ---------------- Mean pool stage 1: 1 wave per 64 sorted nodes, register segment accum ----------------
// batch sorted => <=2 graph segments per 64-node block (boundaries rare); ~100K total atomics
__global__ __launch_bounds__(64) void pool1_kernel(const unsigned* __restrict__ H, const int* __restrict__ batch,
                                                   float* __restrict__ gsum) {
  int j = threadIdx.x;                 // u32 index: dims (2j, 2j+1)
  int n0 = blockIdx.x * 64;
  int n1 = n0 + 64; if (n1 > N_NODES) n1 = N_NODES;
  if (n0 >= N_NODES) return;
  float ax = 0.f, ay = 0.f;
  int gid = batch[n0];
  for (int n = n0; n < n1; ++n) {
    int g = batch[n];
    if (g != gid) {
      atomicAdd(&gsum[(size_t)gid * DD + 2 * j], ax);
      atomicAdd(&gsum[(size_t)gid * DD + 2 * j + 1], ay);
      ax = 0.f; ay = 0.f; gid = g;
    }
    unsigned v = H[(size_t)n * 64 + j];
    ax += bflo(v); ay += bfhi(v);
  }
  atomicAdd(&gsum[(size_t)gid * DD + 2 * j], ax);
  atomicAdd(&gsum[(size_t)gid * DD + 2 * j + 1], ay);
}

__global__ __launch_bounds__(128) void pool2_kernel(const float* __restrict__ gsum, const int* __restrict__ gcnt,
                                                    float* __restrict__ out) {
  int g = blockIdx.x, d = threadIdx.x;
  int c = gcnt[g];
  out[(size_t)g * DD + d] = gsum[(size_t)g * DD + d] / (float)(c > 0 ? c : 1);
}

extern "C" void kernel_launch(void* const* d_in, const int* in_sizes, int n_in,
                              void* d_out, int out_size, void* d_ws, size_t ws_size,
                              hipStream_t stream) {
  const float* x   = (const float*)d_in[0];
  const int*   ei  = (const int*)d_in[1];
  const int*   bat = (const int*)d_in[2];
  const float* W1  = (const float*)d_in[3];
  const float* b1  = (const float*)d_in[4];
  const float* W2  = (const float*)d_in[5];
  const float* b2  = (const float*)d_in[6];
  const int* srcv = ei;
  const int* dstv = ei + N_EDGES;

  char* p = (char*)d_ws;
  auto alloc = [&](size_t bytes) -> char* {
    char* r = p;
    p += (bytes + 255) & ~(size_t)255;
    return r;
  };
  int*            cnt  = (int*)alloc((size_t)N_NODES * 4);
  int*            off  = (int*)alloc((size_t)(N_NODES + 1) * 4);
  int*            nxt  = (int*)alloc((size_t)N_NODES * 4);
  float*          dis  = (float*)alloc((size_t)N_NODES * 4);
  int*            loc  = (int*)alloc((size_t)N_NODES * 4);
  int*            bsum = (int*)alloc((size_t)NSCB * 4);
  int*            boff = (int*)alloc((size_t)NSCB * 4);
  int2*           edge = (int2*)alloc((size_t)N_EDGES * 8);
  unsigned short* WH   = (unsigned short*)alloc((size_t)16 * DD * DD * 2);
  unsigned short* WL   = (unsigned short*)alloc((size_t)16 * DD * DD * 2);
  unsigned short* T    = (unsigned short*)alloc((size_t)MPAD * DD * 2);
  unsigned*       H    = (unsigned*)alloc((size_t)MPAD * 64 * 4);
  float*          gsum = (float*)alloc((size_t)NGRAPHS * DD * 4);
  int*            gcnt = (int*)alloc((size_t)NGRAPHS * 4);
  (void)ws_size; (void)in_sizes; (void)n_in; (void)out_size;

  hipMemsetAsync(cnt, 0, (size_t)N_NODES * 4, stream);
  hipMemsetAsync(gsum, 0, (size_t)NGRAPHS * DD * 4, stream);
  count_kernel<<<(N_EDGES + 255) / 256, 256, 0, stream>>>(dstv, cnt);
  scanA_kernel<<<NSCB, SCB, 0, stream>>>(cnt, loc, bsum);
  scanB_kernel<<<1, 64, 0, stream>>>(bsum, boff, &off[N_NODES]);
  scanC_kernel<<<NSCB, SCB, 0, stream>>>(loc, boff, cnt, off, nxt, dis);
  fill_kernel<<<(N_EDGES + 255) / 256, 256, 0, stream>>>(srcv, dstv, nxt, dis, edge);
  gseg_kernel<<<1, 64, 0, stream>>>(bat, gcnt);
  wprep_kernel<<<(16 * DD * DD + 255) / 256, 256, 0, stream>>>(W1, W2, WH, WL);

  gemm_split_kernel<<<MPAD / 64, 128, 0, stream>>>(x, T, WH, WL, N_NODES);
  for (int c = 0; c < 15; ++c) {
    const float* bias = (c & 1) ? (b2 + (size_t)(c >> 1) * DD) : (b1 + (size_t)(c >> 1) * DD);
    agg_kernel<<<(N_NODES * 64) / 256, 256, 0, stream>>>((const unsigned*)T, H, edge, off, dis,
                                                         bias, (c & 1) ? 0 : 1);
    gemm_bf16_kernel<<<MPAD / 64, 128, 0, stream>>>((const unsigned short*)H, T,
                                                    WH + (size_t)(c + 1) * DD * DD,
                                                    WL + (size_t)(c + 1) * DD * DD, N_NODES);
  }
  // conv 15: plain agg (relu=0) -> H, then low-atomic two-stage mean pool
  agg_kernel<<<(N_NODES * 64) / 256, 256, 0, stream>>>((const unsigned*)T, H, edge, off, dis,
                                                       b2 + 7 * DD, 0);
  pool1_kernel<<<(N_NODES + 63) / 64, 64, 0, stream>>>(H, bat, gsum);
  pool2_kernel<<<NGRAPHS, 128, 0, stream>>>(gsum, gcnt, (float*)d_out);
}

// Round 10
// 1000.484 us; speedup vs baseline: 1.5269x; 1.0020x over previous
//
#include <hip/hip_runtime.h>
#include <hip/hip_bf16.h>

#define N_NODES 50000
#define N_EDGES 600000
#define DD      128
#define NGRAPHS 64
#define MPAD    50048   // 391*128; padded rows written but never consumed
#define SCB     512
#define NSCB    ((N_NODES + SCB - 1) / SCB)   // 98

typedef __attribute__((ext_vector_type(8))) short  short8;
typedef __attribute__((ext_vector_type(4))) float  float4v;

static __device__ __forceinline__ unsigned short f2bf_rne(float f) {
  unsigned u = __builtin_bit_cast(unsigned, f);
  u = (u + 0x7FFFu + ((u >> 16) & 1u)) >> 16;
  return (unsigned short)u;
}
static __device__ __forceinline__ float bf2f(unsigned short h) {
  unsigned u = ((unsigned)h) << 16;
  return __builtin_bit_cast(float, u);
}
static __device__ __forceinline__ float bflo(unsigned u) { return __builtin_bit_cast(float, u << 16); }
static __device__ __forceinline__ float bfhi(unsigned u) { return __builtin_bit_cast(float, u & 0xFFFF0000u); }

// ---------------- CSR build ----------------
__global__ __launch_bounds__(256) void count_kernel(const int* __restrict__ dst, int* __restrict__ cnt) {
  int i = blockIdx.x * 256 + threadIdx.x;
  if (i < N_EDGES) atomicAdd(&cnt[dst[i]], 1);
}

__global__ __launch_bounds__(SCB) void scanA_kernel(const int* __restrict__ cnt, int* __restrict__ loc,
                                                    int* __restrict__ bsum) {
  __shared__ int sm[SCB];
  int t = threadIdx.x;
  int i = blockIdx.x * SCB + t;
  int v = (i < N_NODES) ? cnt[i] : 0;
  sm[t] = v;
  __syncthreads();
  for (int ofs = 1; ofs < SCB; ofs <<= 1) {
    int u = (t >= ofs) ? sm[t - ofs] : 0;
    __syncthreads();
    sm[t] += u;
    __syncthreads();
  }
  if (i < N_NODES) loc[i] = sm[t] - v;
  if (t == SCB - 1) bsum[blockIdx.x] = sm[t];
}

__global__ __launch_bounds__(64) void scanB_kernel(const int* __restrict__ bsum, int* __restrict__ boff,
                                                   int* __restrict__ off_last) {
  if (threadIdx.x == 0) {
    int a = 0;
    for (int b = 0; b < NSCB; ++b) { boff[b] = a; a += bsum[b]; }
    *off_last = a;
  }
}

__global__ __launch_bounds__(SCB) void scanC_kernel(const int* __restrict__ loc, const int* __restrict__ boff,
                                                    const int* __restrict__ cnt, int* __restrict__ off,
                                                    int* __restrict__ nxt, float* __restrict__ dis) {
  int i = blockIdx.x * SCB + threadIdx.x;
  if (i < N_NODES) {
    int o = loc[i] + boff[blockIdx.x];
    off[i] = o; nxt[i] = o;
    dis[i] = rsqrtf((float)(cnt[i] + 1));   // deg includes self-loop
  }
}

// edge weights folded into T' rows (T'[s] = dis[s] * (hW)[s]) -> store src index only
__global__ __launch_bounds__(256) void fill_kernel(const int* __restrict__ src, const int* __restrict__ dst,
                                                   int* __restrict__ nxt, int* __restrict__ csrc) {
  int i = blockIdx.x * 256 + threadIdx.x;
  if (i < N_EDGES) {
    int s = src[i], d = dst[i];
    int pos = atomicAdd(&nxt[d], 1);
    csrc[pos] = s;
  }
}

// batch sorted: per-graph counts via binary search (no atomics — sorted batch makes
// per-node atomicAdd a same-address serialization disaster, measured 234us in R4)
__global__ __launch_bounds__(64) void gseg_kernel(const int* __restrict__ batch, int* __restrict__ gcnt) {
  int g = threadIdx.x;
  int lo = 0, hi = N_NODES;
  while (lo < hi) { int m = (lo + hi) >> 1; if (batch[m] < g) lo = m + 1; else hi = m; }
  int s = lo;
  lo = 0; hi = N_NODES;
  int g1 = g + 1;
  while (lo < hi) { int m = (lo + hi) >> 1; if (batch[m] < g1) lo = m + 1; else hi = m; }
  gcnt[g] = lo - s;
}

// ---------------- W prep: split bf16 hi/lo, transposed to [conv][n][k] ----------------
__global__ __launch_bounds__(256) void wprep_kernel(const float* __restrict__ W1, const float* __restrict__ W2,
                                                    unsigned short* __restrict__ WH, unsigned short* __restrict__ WL) {
  int idx = blockIdx.x * 256 + threadIdx.x;
  if (idx >= 16 * DD * DD) return;
  int c = idx >> 14;          // conv index 0..15
  int r = idx & 16383;
  int n = r >> 7, k = r & 127;
  const float* W = (c & 1) ? W2 : W1;
  float v = W[((size_t)(c >> 1) << 14) + (size_t)k * DD + n];   // W[l][k][n]
  unsigned short h = f2bf_rne(v);
  WH[idx] = h;
  WL[idx] = f2bf_rne(v - bf2f(h));
}

// ---------------- GEMM0: T'(bf16)[M x 128] = dis[row] * (x(f32) @ W0), split-bf16 3-product ----------------
__global__ __launch_bounds__(128) void gemm_split_kernel(const float* __restrict__ A, unsigned short* __restrict__ T,
                                                         const unsigned short* __restrict__ WH,
                                                         const unsigned short* __restrict__ WL,
                                                         const float* __restrict__ dis, int M) {
  const int lane = threadIdx.x & 63;
  const int wave = threadIdx.x >> 6;
  const int Rbase = blockIdx.x * 64 + wave * 32;
  const int lr = lane & 15;
  const int lg = lane >> 4;

  float4v acc[2][8];
#pragma unroll
  for (int i = 0; i < 2; ++i)
#pragma unroll
    for (int j = 0; j < 8; ++j) acc[i][j] = (float4v)0.f;

#pragma unroll
  for (int kk = 0; kk < 4; ++kk) {
    const int k0 = kk * 32 + lg * 8;
    short8 ah[2], al[2];
#pragma unroll
    for (int rf = 0; rf < 2; ++rf) {
      int row = Rbase + rf * 16 + lr;
      row = (row < M) ? row : (M - 1);
      const float* ap = A + (size_t)row * DD + k0;
      float4v x0 = *(const float4v*)ap;
      float4v x1 = *(const float4v*)(ap + 4);
      short8 h, l;
#pragma unroll
      for (int i = 0; i < 4; ++i) {
        unsigned short hb = f2bf_rne(x0[i]);
        h[i] = (short)hb; l[i] = (short)f2bf_rne(x0[i] - bf2f(hb));
      }
#pragma unroll
      for (int i = 0; i < 4; ++i) {
        unsigned short hb = f2bf_rne(x1[i]);
        h[4 + i] = (short)hb; l[4 + i] = (short)f2bf_rne(x1[i] - bf2f(hb));
      }
      ah[rf] = h; al[rf] = l;
    }
#pragma unroll
    for (int n = 0; n < 8; ++n) {
      const size_t wo = (size_t)(n * 16 + lr) * DD + k0;
      short8 bh = *(const short8*)(WH + wo);
      short8 bl = *(const short8*)(WL + wo);
#pragma unroll
      for (int rf = 0; rf < 2; ++rf) {
        acc[rf][n] = __builtin_amdgcn_mfma_f32_16x16x32_bf16(ah[rf], bh, acc[rf][n], 0, 0, 0);
        acc[rf][n] = __builtin_amdgcn_mfma_f32_16x16x32_bf16(al[rf], bh, acc[rf][n], 0, 0, 0);
        acc[rf][n] = __builtin_amdgcn_mfma_f32_16x16x32_bf16(ah[rf], bl, acc[rf][n], 0, 0, 0);
      }
    }
  }
#pragma unroll
  for (int rf = 0; rf < 2; ++rf) {
#pragma unroll
    for (int j = 0; j < 4; ++j) {
      int row = Rbase + rf * 16 + lg * 4 + j;
      int dr = (row < M) ? row : (M - 1);
      float ds_ = dis[dr];
      unsigned short* tp = T + (size_t)row * DD;
#pragma unroll
      for (int n = 0; n < 8; ++n) tp[n * 16 + lr] = f2bf_rne(acc[rf][n][j] * ds_);
    }
  }
}

// ---------------- GEMM (inner convs): T'(bf16) = dis[row] * (H(bf16) @ W), split-B 2-product ----------------
__global__ __launch_bounds__(128) void gemm_bf16_kernel(const unsigned short* __restrict__ H, unsigned short* __restrict__ T,
                                                        const unsigned short* __restrict__ WH,
                                                        const unsigned short* __restrict__ WL,
                                                        const float* __restrict__ dis, int M) {
  const int lane = threadIdx.x & 63;
  const int wave = threadIdx.x >> 6;
  const int Rbase = blockIdx.x * 64 + wave * 32;
  const int lr = lane & 15;
  const int lg = lane >> 4;

  float4v acc[2][8];
#pragma unroll
  for (int i = 0; i < 2; ++i)
#pragma unroll
    for (int j = 0; j < 8; ++j) acc[i][j] = (float4v)0.f;

#pragma unroll
  for (int kk = 0; kk < 4; ++kk) {
    const int k0 = kk * 32 + lg * 8;
    short8 ah[2];
#pragma unroll
    for (int rf = 0; rf < 2; ++rf) {
      int row = Rbase + rf * 16 + lr;
      row = (row < M) ? row : (M - 1);
      ah[rf] = *(const short8*)(H + (size_t)row * DD + k0);
    }
#pragma unroll
    for (int n = 0; n < 8; ++n) {
      const size_t wo = (size_t)(n * 16 + lr) * DD + k0;
      short8 bh = *(const short8*)(WH + wo);
      short8 bl = *(const short8*)(WL + wo);
#pragma unroll
      for (int rf = 0; rf < 2; ++rf) {
        acc[rf][n] = __builtin_amdgcn_mfma_f32_16x16x32_bf16(ah[rf], bh, acc[rf][n], 0, 0, 0);
        acc[rf][n] = __builtin_amdgcn_mfma_f32_16x16x32_bf16(ah[rf], bl, acc[rf][n], 0, 0, 0);
      }
    }
  }
#pragma unroll
  for (int rf = 0; rf < 2; ++rf) {
#pragma unroll
    for (int j = 0; j < 4; ++j) {
      int row = Rbase + rf * 16 + lg * 4 + j;
      int dr = (row < M) ? row : (M - 1);
      float ds_ = dis[dr];
      unsigned short* tp = T + (size_t)row * DD;
#pragma unroll
      for (int n = 0; n < 8; ++n) tp[n * 16 + lr] = f2bf_rne(acc[rf][n][j] * ds_);
    }
  }
}

// ---------------- Aggregation: H = relu?( b + dis[n] * (sum_e T'[src_e] + T'[n]) ) ----------------
// 2 edges per wave-load: lanes 0-31 fetch row of edge e (8B/lane), lanes 32-63 edge e+1.
// Per-half f32 accumulators (4 dims/lane) merged once at the end via shfl_xor(32).
__global__ __launch_bounds__(256) void agg_kernel(const unsigned* __restrict__ t, unsigned* __restrict__ H,
                                                  const int* __restrict__ csrc,
                                                  const int* __restrict__ off, const float* __restrict__ dis,
                                                  const float* __restrict__ bias, int relu) {
  int wid = (int)((blockIdx.x * blockDim.x + threadIdx.x) >> 6);
  int lane = threadIdx.x & 63;
  if (wid >= N_NODES) return;
  int n = __builtin_amdgcn_readfirstlane(wid);
  const int L = lane & 31;
  const int hi = lane >> 5;
  const float sel = hi ? 0.f : 1.f;   // count-once mask for tail & self
  int e0 = off[n], e1 = off[n + 1];

  float a0 = 0.f, a1 = 0.f, a2 = 0.f, a3 = 0.f;

  int e = e0;
  int npairs = (e1 - e0) >> 1;
#pragma unroll 4
  for (int p = 0; p < npairs; ++p, e += 2) {
    int s0 = csrc[e], s1 = csrc[e + 1];
    int sr = hi ? s1 : s0;
    uint2 v = *(const uint2*)(t + (size_t)sr * 64 + 2 * L);
    a0 += bflo(v.x); a1 += bfhi(v.x);
    a2 += bflo(v.y); a3 += bfhi(v.y);
  }
  if (e < e1) {                       // odd tail: low half only
    int s0 = csrc[e];
    uint2 v = *(const uint2*)(t + (size_t)s0 * 64 + 2 * L);
    a0 += sel * bflo(v.x); a1 += sel * bfhi(v.x);
    a2 += sel * bflo(v.y); a3 += sel * bfhi(v.y);
  }
  {                                   // self-loop (already dis[n]-scaled in T')
    uint2 v = *(const uint2*)(t + (size_t)n * 64 + 2 * L);
    a0 += sel * bflo(v.x); a1 += sel * bfhi(v.x);
    a2 += sel * bflo(v.y); a3 += sel * bfhi(v.y);
  }
  a0 += __shfl_xor(a0, 32);
  a1 += __shfl_xor(a1, 32);
  a2 += __shfl_xor(a2, 32);
  a3 += __shfl_xor(a3, 32);

  float dn = dis[n];
  float4v bb = *(const float4v*)(bias + 4 * L);
  float r0 = dn * a0 + bb[0];
  float r1 = dn * a1 + bb[1];
  float r2 = dn * a2 + bb[2];
  float r3 = dn * a3 + bb[3];
  if (relu) { r0 = fmaxf(r0, 0.f); r1 = fmaxf(r1, 0.f); r2 = fmaxf(r2, 0.f); r3 = fmaxf(r3, 0.f); }
  if (hi == 0) {
    uint2 o;
    o.x = (unsigned)f2bf_rne(r0) | ((unsigned)f2bf_rne(r1) << 16);
    o.y = (unsigned)f2bf_rne(r2) | ((unsigned)f2bf_rne(r3) << 16);
    *(uint2*)(H + (size_t)n * 64 + 2 * L) = o;
  }
}

// ---------------- Mean pool stage 1: 1 wave per 64 sorted nodes, register segment accum ----------------
__global__ __launch_bounds__(64) void pool1_kernel(const unsigned* __restrict__ H, const int* __restrict__ batch,
                                                   float* __restrict__ gsum) {
  int j = threadIdx.x;                 // u32 index: dims (2j, 2j+1)
  int n0 = blockIdx.x * 64;
  int n1 = n0 + 64; if (n1 > N_NODES) n1 = N_NODES;
  if (n0 >= N_NODES) return;
  float ax = 0.f, ay = 0.f;
  int gid = batch[n0];
  for (int n = n0; n < n1; ++n) {
    int g = batch[n];
    if (g != gid) {
      atomicAdd(&gsum[(size_t)gid * DD + 2 * j], ax);
      atomicAdd(&gsum[(size_t)gid * DD + 2 * j + 1], ay);
      ax = 0.f; ay = 0.f; gid = g;
    }
    unsigned v = H[(size_t)n * 64 + j];
    ax += bflo(v); ay += bfhi(v);
  }
  atomicAdd(&gsum[(size_t)gid * DD + 2 * j], ax);
  atomicAdd(&gsum[(size_t)gid * DD + 2 * j + 1], ay);
}

__global__ __launch_bounds__(128) void pool2_kernel(const float* __restrict__ gsum, const int* __restrict__ gcnt,
                                                    float* __restrict__ out) {
  int g = blockIdx.x, d = threadIdx.x;
  int c = gcnt[g];
  out[(size_t)g * DD + d] = gsum[(size_t)g * DD + d] / (float)(c > 0 ? c : 1);
}

extern "C" void kernel_launch(void* const* d_in, const int* in_sizes, int n_in,
                              void* d_out, int out_size, void* d_ws, size_t ws_size,
                              hipStream_t stream) {
  const float* x   = (const float*)d_in[0];
  const int*   ei  = (const int*)d_in[1];
  const int*   bat = (const int*)d_in[2];
  const float* W1  = (const float*)d_in[3];
  const float* b1  = (const float*)d_in[4];
  const float* W2  = (const float*)d_in[5];
  const float* b2  = (const float*)d_in[6];
  const int* srcv = ei;
  const int* dstv = ei + N_EDGES;

  char* p = (char*)d_ws;
  auto alloc = [&](size_t bytes) -> char* {
    char* r = p;
    p += (bytes + 255) & ~(size_t)255;
    return r;
  };
  int*            cnt  = (int*)alloc((size_t)N_NODES * 4);
  int*            off  = (int*)alloc((size_t)(N_NODES + 1) * 4);
  int*            nxt  = (int*)alloc((size_t)N_NODES * 4);
  float*          dis  = (float*)alloc((size_t)N_NODES * 4);
  int*            loc  = (int*)alloc((size_t)N_NODES * 4);
  int*            bsum = (int*)alloc((size_t)NSCB * 4);
  int*            boff = (int*)alloc((size_t)NSCB * 4);
  int*            csrc = (int*)alloc((size_t)N_EDGES * 4);
  unsigned short* WH   = (unsigned short*)alloc((size_t)16 * DD * DD * 2);
  unsigned short* WL   = (unsigned short*)alloc((size_t)16 * DD * DD * 2);
  unsigned short* T    = (unsigned short*)alloc((size_t)MPAD * DD * 2);
  unsigned*       H    = (unsigned*)alloc((size_t)MPAD * 64 * 4);
  float*          gsum = (float*)alloc((size_t)NGRAPHS * DD * 4);
  int*            gcnt = (int*)alloc((size_t)NGRAPHS * 4);
  (void)ws_size; (void)in_sizes; (void)n_in; (void)out_size;

  hipMemsetAsync(cnt, 0, (size_t)N_NODES * 4, stream);
  hipMemsetAsync(gsum, 0, (size_t)NGRAPHS * DD * 4, stream);
  count_kernel<<<(N_EDGES + 255) / 256, 256, 0, stream>>>(dstv, cnt);
  scanA_kernel<<<NSCB, SCB, 0, stream>>>(cnt, loc, bsum);
  scanB_kernel<<<1, 64, 0, stream>>>(bsum, boff, &off[N_NODES]);
  scanC_kernel<<<NSCB, SCB, 0, stream>>>(loc, boff, cnt, off, nxt, dis);
  fill_kernel<<<(N_EDGES + 255) / 256, 256, 0, stream>>>(srcv, dstv, nxt, csrc);
  gseg_kernel<<<1, 64, 0, stream>>>(bat, gcnt);
  wprep_kernel<<<(16 * DD * DD + 255) / 256, 256, 0, stream>>>(W1, W2, WH, WL);

  gemm_split_kernel<<<MPAD / 64, 128, 0, stream>>>(x, T, WH, WL, dis, N_NODES);
  for (int c = 0; c < 15; ++c) {
    const float* bias = (c & 1) ? (b2 + (size_t)(c >> 1) * DD) : (b1 + (size_t)(c >> 1) * DD);
    agg_kernel<<<(N_NODES * 64) / 256, 256, 0, stream>>>((const unsigned*)T, H, csrc, off, dis,
                                                         bias, (c & 1) ? 0 : 1);
    gemm_bf16_kernel<<<MPAD / 64, 128, 0, stream>>>((const unsigned short*)H, T,
                                                    WH + (size_t)(c + 1) * DD * DD,
                                                    WL + (size_t)(c + 1) * DD * DD, dis, N_NODES);
  }
  // conv 15: plain agg (relu=0) -> H, then low-atomic two-stage mean pool
  agg_kernel<<<(N_NODES * 64) / 256, 256, 0, stream>>>((const unsigned*)T, H, csrc, off, dis,
                                                       b2 + 7 * DD, 0);
  pool1_kernel<<<(N_NODES + 63) / 64, 64, 0, stream>>>(H, bat, gsum);
  pool2_kernel<<<NGRAPHS, 128, 0, stream>>>(gsum, gcnt, (float*)d_out);
}